// Round 13
// baseline (337.132 us; speedup 1.0000x reference)
//
#include <hip/hip_runtime.h>
#include <hip/hip_bf16.h>

#define NB 512
#define CIN 32
#define LEN 512
#define NE 8
#define NPOOL 16
#define DIN 16384
#define DOUT 768
#define HD 1024
#define F1 128

#define BK 32        // K per MFMA step
#define MFR 10       // m-fragments per wave -> 160 rows (covers cn in one pass)
#define KSPLIT 16    // K chunks (kch = 1024, NS = 32)
#define NSTRIP 24    // 24 col-strips of 32 over DOUT=768

typedef __attribute__((ext_vector_type(4))) float f32x4;
typedef __attribute__((ext_vector_type(8))) short s16x8;
typedef __attribute__((ext_vector_type(4))) unsigned int u32x4;

__device__ __forceinline__ float gelu_erf(float v) {
    return 0.5f * v * (1.0f + erff(v * 0.70710678118654752f));
}

__device__ __forceinline__ unsigned cvt_pk(float lo, float hi) {
    unsigned r;
    asm volatile("v_cvt_pk_bf16_f32 %0, %1, %2" : "=v"(r) : "v"(lo), "v"(hi));
    return r;
}

__device__ __forceinline__ unsigned short f2bf_u(float f) {
    union { float f; unsigned u; } x; x.f = f;
    unsigned r = x.u + 0x7fffu + ((x.u >> 16) & 1u);
    return (unsigned short)(r >> 16);
}

// ---------------- Kernel A: conv1d + GELU + avgpool + BN; also emits bf16 x ----------------
__global__ __launch_bounds__(256) void krouter_conv(
    const float* __restrict__ x, const float* __restrict__ cw, const float* __restrict__ cb,
    const float* __restrict__ bng, const float* __restrict__ bnb,
    const float* __restrict__ bnm, const float* __restrict__ bnv,
    float* __restrict__ h, int* __restrict__ cnt, unsigned short* __restrict__ xbuf)
{
    __shared__ float xs[CIN * 264];
    int half = blockIdx.x;
    int b = blockIdx.y;
    int t = threadIdx.x;
    if (b == 0 && half == 0 && t < NE) cnt[t] = 0;

    int Lchunk0 = half * 64 - 1;
    const float* xb_ = x + (size_t)b * DIN;
    for (int idx = t; idx < CIN * 66; idx += 256) {
        int ci = idx / 66;
        int cc = idx - ci * 66;
        int gc = min(max(Lchunk0 + cc, 0), 127);
        f32x4 v = *(const f32x4*)(xb_ + ci * 512 + gc * 4);
        int byte = ci * 1056 + ((cc << 4) ^ (((cc >> 3) & 7) << 4));
        *(f32x4*)((char*)xs + byte) = v;
        if (cc >= 1 && cc <= 64) {
            int gc2 = Lchunk0 + cc;
            unsigned lo = cvt_pk(v[0], v[1]);
            unsigned hi = cvt_pk(v[2], v[3]);
            unsigned long long pk8 = ((unsigned long long)hi << 32) | lo;
            *(unsigned long long*)((char*)xbuf
                + ((size_t)b * DIN + ci * 512 + gc2 * 4) * 2) = pk8;
        }
    }
    __syncthreads();

    int p  = t & 7;
    int pg = half * 8 + p;
    int cq = t >> 3;
    int co0 = cq * 2, co1 = co0 + 1;

    float sa[32], sb[32];
    #pragma unroll
    for (int i = 0; i < 32; ++i) { sa[i] = 0.f; sb[i] = 0.f; }

    for (int ci = 0; ci < CIN; ++ci) {
        float f[40];
        #pragma unroll
        for (int u = 0; u < 10; ++u) {
            int lc = p * 8 + u;
            int byte = ci * 1056 + ((lc << 4) ^ (((lc >> 3) & 7) << 4));
            f32x4 v = *(const f32x4*)((const char*)xs + byte);
            f[4*u+0] = v[0]; f[4*u+1] = v[1]; f[4*u+2] = v[2]; f[4*u+3] = v[3];
        }
        if (pg == 0)  f[3]  = 0.f;
        if (pg == 15) f[36] = 0.f;
        float wa0 = cw[co0*96 + ci*3 + 0], wa1 = cw[co0*96 + ci*3 + 1], wa2 = cw[co0*96 + ci*3 + 2];
        float wb0 = cw[co1*96 + ci*3 + 0], wb1 = cw[co1*96 + ci*3 + 1], wb2 = cw[co1*96 + ci*3 + 2];
        #pragma unroll
        for (int i = 0; i < 32; ++i) {
            sa[i] = fmaf(f[i+3], wa0, fmaf(f[i+4], wa1, fmaf(f[i+5], wa2, sa[i])));
            sb[i] = fmaf(f[i+3], wb0, fmaf(f[i+4], wb1, fmaf(f[i+5], wb2, sb[i])));
        }
    }

    float ba = cb[co0], bbv = cb[co1];
    float ma = 0.f, mb = 0.f;
    #pragma unroll
    for (int i = 0; i < 32; ++i) { ma += gelu_erf(sa[i] + ba); mb += gelu_erf(sb[i] + bbv); }
    ma *= (1.f / 32.f); mb *= (1.f / 32.f);

    int oa = co0 * NPOOL + pg, ob = co1 * NPOOL + pg;
    float ra = (ma - bnm[oa]) * rsqrtf(bnv[oa] + 1e-5f) * bng[oa] + bnb[oa];
    float rb = (mb - bnm[ob]) * rsqrtf(bnv[ob] + 1e-5f) * bng[ob] + bnb[ob];
    h[(size_t)b * HD + oa] = ra;
    h[(size_t)b * HD + ob] = rb;
}

// ---------------- Kernel B: fc1+GELU, fc2, gumbel softmax, top-2 (4 rows/block) ------------
__global__ __launch_bounds__(256) void krouter_fc(
    const float* __restrict__ h, const float* __restrict__ f1w, const float* __restrict__ f1b,
    const float* __restrict__ f2w, const float* __restrict__ f2b,
    const float* __restrict__ gu,
    int* __restrict__ top2e, float* __restrict__ top2w,
    int* __restrict__ cnt, int* __restrict__ rowlist, float* __restrict__ roww)
{
    __shared__ float hs[4 * HD];
    __shared__ float h1s[4 * F1];
    __shared__ float lg[4 * NE];

    int bb = blockIdx.x * 4;
    int t = threadIdx.x;

    const f32x4* hg = (const f32x4*)(h + (size_t)bb * HD);
    f32x4* hs4 = (f32x4*)hs;
    #pragma unroll
    for (int u = 0; u < 4; ++u) hs4[t + 256 * u] = hg[t + 256 * u];
    __syncthreads();

    int j = t & 127;
    int pr = t >> 7;
    float acc[2] = {0.f, 0.f};
    const f32x4* w4 = (const f32x4*)(f1w + (size_t)j * HD);
    for (int k4 = 0; k4 < 256; ++k4) {
        f32x4 w = w4[k4];
        #pragma unroll
        for (int g = 0; g < 2; ++g) {
            f32x4 hv = hs4[(pr * 2 + g) * 256 + k4];
            acc[g] += w[0]*hv[0] + w[1]*hv[1] + w[2]*hv[2] + w[3]*hv[3];
        }
    }
    float bj = f1b[j];
    #pragma unroll
    for (int g = 0; g < 2; ++g) h1s[(pr * 2 + g) * F1 + j] = gelu_erf(acc[g] + bj);
    __syncthreads();

    if (t < 32) {
        int bi = t >> 3, e = t & 7;
        float s = f2b[e];
        const float* w = f2w + e * F1;
        const float* hh = h1s + bi * F1;
        #pragma unroll 8
        for (int k = 0; k < F1; ++k) s += hh[k] * w[k];
        lg[bi * NE + e] = s;
    }
    __syncthreads();

    if (t < 4) {
        int bi = t; int b = bb + bi;
        float r[NE];
        float mx = -1e30f;
        #pragma unroll
        for (int e = 0; e < NE; ++e) {
            float g = -logf(-logf(gu[b * NE + e]));
            r[e] = lg[bi * NE + e] + g;
            mx = fmaxf(mx, r[e]);
        }
        float sum = 0.f;
        #pragma unroll
        for (int e = 0; e < NE; ++e) { r[e] = expf(r[e] - mx); sum += r[e]; }
        float inv = 1.f / sum;
        #pragma unroll
        for (int e = 0; e < NE; ++e) r[e] *= inv;
        int e0 = 0; float v0 = r[0];
        #pragma unroll
        for (int e = 1; e < NE; ++e) if (r[e] > v0) { v0 = r[e]; e0 = e; }
        int e1 = -1; float v1 = -1.f;
        #pragma unroll
        for (int e = 0; e < NE; ++e) { if (e == e0) continue; if (r[e] > v1) { v1 = r[e]; e1 = e; } }
        float den = v0 + v1 + 1e-8f;
        float w0 = v0 / den, w1 = v1 / den;
        top2e[b * 2 + 0] = e0; top2e[b * 2 + 1] = e1;
        top2w[b * 2 + 0] = w0; top2w[b * 2 + 1] = w1;
        int p0 = atomicAdd(&cnt[e0], 1);
        rowlist[e0 * NB + p0] = b * 2 + 0; roww[e0 * NB + p0] = w0;
        int p1 = atomicAdd(&cnt[e1], 1);
        rowlist[e1 * NB + p1] = b * 2 + 1; roww[e1 * NB + p1] = w1;
    }
}

// ---------------- Kernel C: gathered expert GEMM — free-running waves, no LDS, no barriers -
// Each WAVE owns (expert e, 32-col strip st, K-chunk kc): 160 rows x 32 cols x 1024 K.
// B streamed global->regs (16 dword/step, coalesced 256B/instr); A-frags gathered per-lane
// from bf16 xbuf (base+imm offsets). Register double-buffer, even/odd unrolled (static
// indexing). Compiler emits counted vmcnt automatically -- nothing ever drains the queue.
// grid 768 = 8e x 16kc x 6bg (4 waves/block = 4 strips), XCD-swizzled: expert per XCD.
__global__ __launch_bounds__(256, 2) void kgemm(
    const unsigned short* __restrict__ xb, const float* __restrict__ ew,
    const int* __restrict__ cnt, const int* __restrict__ rowlist, const float* __restrict__ roww,
    unsigned short* __restrict__ ypart, int kch)
{
    int nwg = gridDim.x;                  // 768
    int cpx = nwg >> 3;                   // 96 per XCD
    int wg = (blockIdx.x & 7) * cpx + (blockIdx.x >> 3);
    int e  = wg / (KSPLIT * 6);           // one expert per XCD
    int r  = wg % (KSPLIT * 6);
    int kc = r / 6;
    int bg = r % 6;

    int t = threadIdx.x;
    int wid = t >> 6, lane = t & 63;
    int st = bg * 4 + wid;                // col strip 0..23
    int g = lane >> 4;                    // k-slice group 0..3
    int cn = cnt[e];
    int NS = kch / BK;                    // 32
    int k0 = kc * kch;

    // per-lane B base: row k0+g*8, col st*32+(lane&15)
    const char* gpB = (const char*)ew + (size_t)e * DIN * DOUT * 4
                    + ((size_t)k0 + g * 8) * (DOUT * 4)
                    + (size_t)(st * 32 + (lane & 15)) * 4;

#define LOADA(AS, s_)                                                    \
    _Pragma("unroll")                                                    \
    for (int mi = 0; mi < MFR; ++mi)                                     \
        AS[mi] = *(const s16x8*)(abase[mi] + (s_) * (BK * 2));

#define LOADB(BS, s_) {                                                  \
    const char* bp_ = gpB + (size_t)(s_) * ((size_t)BK * DOUT * 4);      \
    _Pragma("unroll")                                                    \
    for (int nf = 0; nf < 2; ++nf)                                       \
        _Pragma("unroll")                                                \
        for (int i = 0; i < 8; ++i)                                      \
            BS[nf][i] = *(const float*)(bp_ + (size_t)i * (DOUT * 4) + nf * 64); }

#define STEP(AC, BC, AN, BN, s_) {                                       \
    if ((s_) + 1 < NS) { LOADA(AN, (s_) + 1); LOADB(BN, (s_) + 1); }     \
    _Pragma("unroll")                                                    \
    for (int nf = 0; nf < 2; ++nf) {                                     \
        union { u32x4 u; s16x8 v8; } bf_;                                \
        bf_.u[0] = cvt_pk(BC[nf][0], BC[nf][1]);                         \
        bf_.u[1] = cvt_pk(BC[nf][2], BC[nf][3]);                         \
        bf_.u[2] = cvt_pk(BC[nf][4], BC[nf][5]);                         \
        bf_.u[3] = cvt_pk(BC[nf][6], BC[nf][7]);                         \
        _Pragma("unroll")                                                \
        for (int mi = 0; mi < MFR; ++mi)                                 \
            acc[mi][nf] = __builtin_amdgcn_mfma_f32_16x16x32_bf16(       \
                AC[mi], bf_.v8, acc[mi][nf], 0, 0, 0);                   \
    } }

    for (int row0 = 0; row0 < cn; row0 += 16 * MFR) {
        // per-lane A gather bases (row clamped; clamped rows masked at write)
        const char* abase[MFR];
        #pragma unroll
        for (int mi = 0; mi < MFR; ++mi) {
            int m = min(row0 + mi * 16 + (lane & 15), cn - 1);
            int row = rowlist[e * NB + m] >> 1;
            abase[mi] = (const char*)xb + (size_t)row * (DIN * 2)
                      + (size_t)k0 * 2 + g * 16;
        }

        f32x4 acc[MFR][2];
        #pragma unroll
        for (int i = 0; i < MFR; ++i) {
            acc[i][0] = (f32x4){0.f, 0.f, 0.f, 0.f};
            acc[i][1] = (f32x4){0.f, 0.f, 0.f, 0.f};
        }

        s16x8 A0[MFR], A1[MFR];
        float B0[2][8], B1[2][8];

        LOADA(A0, 0);
        LOADB(B0, 0);
        for (int s = 0; s < NS; s += 2) {
            STEP(A0, B0, A1, B1, s);
            STEP(A1, B1, A0, B0, s + 1);
        }

        // epilogue: gate weight, bf16 scatter to per-(slot,kc) partial plane
        #pragma unroll
        for (int mi = 0; mi < MFR; ++mi) {
            #pragma unroll
            for (int rg = 0; rg < 4; ++rg) {
                int m = row0 + mi * 16 + g * 4 + rg;
                if (m < cn) {
                    int ent = rowlist[e * NB + m];
                    float wgt = roww[e * NB + m];
                    int ob = ent >> 1, slot = ent & 1;
                    unsigned short* dst = ypart
                        + ((size_t)(slot * KSPLIT + kc) * NB + ob) * DOUT
                        + st * 32 + (lane & 15);
                    dst[0]  = f2bf_u(acc[mi][0][rg] * wgt);
                    dst[16] = f2bf_u(acc[mi][1][rg] * wgt);
                }
            }
        }
    }
#undef LOADA
#undef LOADB
#undef STEP
}

// ---------------- Kernel D: combine bf16 partial planes + weighted expert bias ------------
__global__ __launch_bounds__(256) void kcombine(
    const unsigned short* __restrict__ ypart,
    const int* __restrict__ top2e, const float* __restrict__ top2w,
    const float* __restrict__ eb, float* __restrict__ out, int nplanes)
{
    int b = blockIdx.y;
    int n = blockIdx.x * 256 + threadIdx.x;
    float s = 0.f;
    for (int p = 0; p < nplanes; ++p) {
        unsigned v = ypart[((size_t)p * NB + b) * DOUT + n];
        union { unsigned u; float f; } c; c.u = v << 16;
        s += c.f;
    }
    int e0 = top2e[b * 2], e1 = top2e[b * 2 + 1];
    float w0 = top2w[b * 2], w1 = top2w[b * 2 + 1];
    s += w0 * eb[e0 * DOUT + n] + w1 * eb[e1 * DOUT + n];
    out[(size_t)b * DOUT + n] = s;
}

extern "C" void kernel_launch(void* const* d_in, const int* in_sizes, int n_in,
                              void* d_out, int out_size, void* d_ws, size_t ws_size,
                              hipStream_t stream)
{
    const float* x   = (const float*)d_in[0];
    const float* gu  = (const float*)d_in[1];
    const float* cw  = (const float*)d_in[2];
    const float* cb  = (const float*)d_in[3];
    const float* bng = (const float*)d_in[4];
    const float* bnb = (const float*)d_in[5];
    const float* bnm = (const float*)d_in[6];
    const float* bnv = (const float*)d_in[7];
    const float* f1w = (const float*)d_in[8];
    const float* f1b = (const float*)d_in[9];
    const float* f2w = (const float*)d_in[10];
    const float* f2b = (const float*)d_in[11];
    const float* ew  = (const float*)d_in[12];
    const float* eb  = (const float*)d_in[13];

    int kch = DIN / KSPLIT;   // 1024

    char* ws = (char*)d_ws;
    size_t off = 0;
    float* h       = (float*)(ws + off); off += (size_t)NB * HD * 4;
    int*   top2e   = (int*)(ws + off);   off += (size_t)NB * 2 * 4;
    float* top2w   = (float*)(ws + off); off += (size_t)NB * 2 * 4;
    int*   cnt     = (int*)(ws + off);   off += 256;
    int*   rowlist = (int*)(ws + off);   off += (size_t)NE * NB * 4;
    float* roww    = (float*)(ws + off); off += (size_t)NE * NB * 4;
    unsigned short* xbuf = (unsigned short*)(ws + off);
    off += (size_t)NB * DIN * 2;
    unsigned short* ypart = (unsigned short*)(ws + off);
    off += (size_t)2 * KSPLIT * NB * DOUT * 2;

    krouter_conv<<<dim3(2, NB), 256, 0, stream>>>(x, cw, cb, bng, bnb, bnm, bnv, h, cnt, xbuf);
    krouter_fc<<<NB / 4, 256, 0, stream>>>(h, f1w, f1b, f2w, f2b, gu,
                                           top2e, top2w, cnt, rowlist, roww);
    kgemm<<<NE * KSPLIT * 6, 256, 0, stream>>>(xbuf, ew, cnt, rowlist, roww, ypart, kch);
    kcombine<<<dim3(3, NB), 256, 0, stream>>>(ypart, top2e, top2w, eb, (float*)d_out,
                                              2 * KSPLIT);
}

// Round 14
// 235.667 us; speedup vs baseline: 1.4305x; 1.4305x over previous
//
#include <hip/hip_runtime.h>
#include <hip/hip_bf16.h>

#define NB 512
#define CIN 32
#define LEN 512
#define NE 8
#define NPOOL 16
#define DIN 16384
#define DOUT 768
#define HD 1024
#define F1 128

#define MT 256      // M tile = whole expert
#define NT 128      // N tile (6 per DOUT)
#define BK 64       // K per step

typedef __attribute__((ext_vector_type(4))) float f32x4;
typedef __attribute__((ext_vector_type(8))) short s16x8;
typedef __attribute__((ext_vector_type(4))) unsigned int u32x4;

__device__ __forceinline__ float gelu_erf(float v) {
    return 0.5f * v * (1.0f + erff(v * 0.70710678118654752f));
}

__device__ __forceinline__ unsigned cvt_pk(float lo, float hi) {
    unsigned r;
    asm volatile("v_cvt_pk_bf16_f32 %0, %1, %2" : "=v"(r) : "v"(lo), "v"(hi));
    return r;
}

__device__ __forceinline__ unsigned short f2bf_u(float f) {
    union { float f; unsigned u; } x; x.f = f;
    unsigned r = x.u + 0x7fffu + ((x.u >> 16) & 1u);
    return (unsigned short)(r >> 16);
}

__device__ __forceinline__ void gload_lds16(const void* gptr, void* lptr) {
    __builtin_amdgcn_global_load_lds(
        (const __attribute__((address_space(1))) unsigned int*)gptr,
        (__attribute__((address_space(3))) unsigned int*)lptr,
        16, 0, 0);
}

// ---------------- Kernel A: conv1d + GELU + avgpool + BN; also emits bf16 x ----------------
__global__ __launch_bounds__(256) void krouter_conv(
    const float* __restrict__ x, const float* __restrict__ cw, const float* __restrict__ cb,
    const float* __restrict__ bng, const float* __restrict__ bnb,
    const float* __restrict__ bnm, const float* __restrict__ bnv,
    float* __restrict__ h, int* __restrict__ cnt, unsigned short* __restrict__ xbuf)
{
    __shared__ float xs[CIN * 264];
    int half = blockIdx.x;
    int b = blockIdx.y;
    int t = threadIdx.x;
    if (b == 0 && half == 0 && t < NE) cnt[t] = 0;

    int Lchunk0 = half * 64 - 1;
    const float* xb_ = x + (size_t)b * DIN;
    for (int idx = t; idx < CIN * 66; idx += 256) {
        int ci = idx / 66;
        int cc = idx - ci * 66;
        int gc = min(max(Lchunk0 + cc, 0), 127);
        f32x4 v = *(const f32x4*)(xb_ + ci * 512 + gc * 4);
        int byte = ci * 1056 + ((cc << 4) ^ (((cc >> 3) & 7) << 4));
        *(f32x4*)((char*)xs + byte) = v;
        if (cc >= 1 && cc <= 64) {
            int gc2 = Lchunk0 + cc;
            unsigned lo = cvt_pk(v[0], v[1]);
            unsigned hi = cvt_pk(v[2], v[3]);
            unsigned long long pk8 = ((unsigned long long)hi << 32) | lo;
            *(unsigned long long*)((char*)xbuf
                + ((size_t)b * DIN + ci * 512 + gc2 * 4) * 2) = pk8;
        }
    }
    __syncthreads();

    int p  = t & 7;
    int pg = half * 8 + p;
    int cq = t >> 3;
    int co0 = cq * 2, co1 = co0 + 1;

    float sa[32], sb[32];
    #pragma unroll
    for (int i = 0; i < 32; ++i) { sa[i] = 0.f; sb[i] = 0.f; }

    for (int ci = 0; ci < CIN; ++ci) {
        float f[40];
        #pragma unroll
        for (int u = 0; u < 10; ++u) {
            int lc = p * 8 + u;
            int byte = ci * 1056 + ((lc << 4) ^ (((lc >> 3) & 7) << 4));
            f32x4 v = *(const f32x4*)((const char*)xs + byte);
            f[4*u+0] = v[0]; f[4*u+1] = v[1]; f[4*u+2] = v[2]; f[4*u+3] = v[3];
        }
        if (pg == 0)  f[3]  = 0.f;
        if (pg == 15) f[36] = 0.f;
        float wa0 = cw[co0*96 + ci*3 + 0], wa1 = cw[co0*96 + ci*3 + 1], wa2 = cw[co0*96 + ci*3 + 2];
        float wb0 = cw[co1*96 + ci*3 + 0], wb1 = cw[co1*96 + ci*3 + 1], wb2 = cw[co1*96 + ci*3 + 2];
        #pragma unroll
        for (int i = 0; i < 32; ++i) {
            sa[i] = fmaf(f[i+3], wa0, fmaf(f[i+4], wa1, fmaf(f[i+5], wa2, sa[i])));
            sb[i] = fmaf(f[i+3], wb0, fmaf(f[i+4], wb1, fmaf(f[i+5], wb2, sb[i])));
        }
    }

    float ba = cb[co0], bbv = cb[co1];
    float ma = 0.f, mb = 0.f;
    #pragma unroll
    for (int i = 0; i < 32; ++i) { ma += gelu_erf(sa[i] + ba); mb += gelu_erf(sb[i] + bbv); }
    ma *= (1.f / 32.f); mb *= (1.f / 32.f);

    int oa = co0 * NPOOL + pg, ob = co1 * NPOOL + pg;
    float ra = (ma - bnm[oa]) * rsqrtf(bnv[oa] + 1e-5f) * bng[oa] + bnb[oa];
    float rb = (mb - bnm[ob]) * rsqrtf(bnv[ob] + 1e-5f) * bng[ob] + bnb[ob];
    h[(size_t)b * HD + oa] = ra;
    h[(size_t)b * HD + ob] = rb;
}

// ---------------- Kernel B: fc1+GELU, fc2, gumbel softmax, top-2 (4 rows/block) ------------
__global__ __launch_bounds__(256) void krouter_fc(
    const float* __restrict__ h, const float* __restrict__ f1w, const float* __restrict__ f1b,
    const float* __restrict__ f2w, const float* __restrict__ f2b,
    const float* __restrict__ gu,
    int* __restrict__ top2e, float* __restrict__ top2w,
    int* __restrict__ cnt, int* __restrict__ rowlist, float* __restrict__ roww)
{
    __shared__ float hs[4 * HD];
    __shared__ float h1s[4 * F1];
    __shared__ float lg[4 * NE];

    int bb = blockIdx.x * 4;
    int t = threadIdx.x;

    const f32x4* hg = (const f32x4*)(h + (size_t)bb * HD);
    f32x4* hs4 = (f32x4*)hs;
    #pragma unroll
    for (int u = 0; u < 4; ++u) hs4[t + 256 * u] = hg[t + 256 * u];
    __syncthreads();

    int j = t & 127;
    int pr = t >> 7;
    float acc[2] = {0.f, 0.f};
    const f32x4* w4 = (const f32x4*)(f1w + (size_t)j * HD);
    for (int k4 = 0; k4 < 256; ++k4) {
        f32x4 w = w4[k4];
        #pragma unroll
        for (int g = 0; g < 2; ++g) {
            f32x4 hv = hs4[(pr * 2 + g) * 256 + k4];
            acc[g] += w[0]*hv[0] + w[1]*hv[1] + w[2]*hv[2] + w[3]*hv[3];
        }
    }
    float bj = f1b[j];
    #pragma unroll
    for (int g = 0; g < 2; ++g) h1s[(pr * 2 + g) * F1 + j] = gelu_erf(acc[g] + bj);
    __syncthreads();

    if (t < 32) {
        int bi = t >> 3, e = t & 7;
        float s = f2b[e];
        const float* w = f2w + e * F1;
        const float* hh = h1s + bi * F1;
        #pragma unroll 8
        for (int k = 0; k < F1; ++k) s += hh[k] * w[k];
        lg[bi * NE + e] = s;
    }
    __syncthreads();

    if (t < 4) {
        int bi = t; int b = bb + bi;
        float r[NE];
        float mx = -1e30f;
        #pragma unroll
        for (int e = 0; e < NE; ++e) {
            float g = -logf(-logf(gu[b * NE + e]));
            r[e] = lg[bi * NE + e] + g;
            mx = fmaxf(mx, r[e]);
        }
        float sum = 0.f;
        #pragma unroll
        for (int e = 0; e < NE; ++e) { r[e] = expf(r[e] - mx); sum += r[e]; }
        float inv = 1.f / sum;
        #pragma unroll
        for (int e = 0; e < NE; ++e) r[e] *= inv;
        int e0 = 0; float v0 = r[0];
        #pragma unroll
        for (int e = 1; e < NE; ++e) if (r[e] > v0) { v0 = r[e]; e0 = e; }
        int e1 = -1; float v1 = -1.f;
        #pragma unroll
        for (int e = 0; e < NE; ++e) { if (e == e0) continue; if (r[e] > v1) { v1 = r[e]; e1 = e; } }
        float den = v0 + v1 + 1e-8f;
        float w0 = v0 / den, w1 = v1 / den;
        top2e[b * 2 + 0] = e0; top2e[b * 2 + 1] = e1;
        top2w[b * 2 + 0] = w0; top2w[b * 2 + 1] = w1;
        int p0 = atomicAdd(&cnt[e0], 1);
        rowlist[e0 * NB + p0] = b * 2 + 0; roww[e0 * NB + p0] = w0;
        int p1 = atomicAdd(&cnt[e1], 1);
        rowlist[e1 * NB + p1] = b * 2 + 1; roww[e1 * NB + p1] = w1;
    }
}

// ---------------- Kernel C: expert GEMM, producer/consumer wave specialization -------------
// 768 thr = 4 producer waves (pure streaming) + 8 consumer waves (pure MFMA).
// Producers: 8x f32x4 B-loads -> ds_write_b128 (fp32 copy, deep vmcnt pipeline like a copy
// kernel) + 8x A gather-DMA (bf16 xbuf, pre-swizzled source), one step ahead into dbuf.
// Consumers: tile 64x64, A via single ds_read_b128 frags (XOR-swz), B fp32 reads + cvt_pk.
// One __syncthreads per step: everything it drains is a full step old -> costs ~0.
__global__ __launch_bounds__(768, 3) void kgemm(
    const unsigned short* __restrict__ xb, const float* __restrict__ ew,
    const int* __restrict__ cnt, const int* __restrict__ rowlist, const float* __restrict__ roww,
    unsigned short* __restrict__ ypart, int nkc, int kch)
{
    int nwg = gridDim.x;
    int cpx = nwg >> 3;
    int wg = (blockIdx.x & 7) * cpx + (blockIdx.x >> 3);
    int nt = wg % 6;
    int kc = (wg / 6) % nkc;
    int e  = wg / (6 * nkc);
    int cn = cnt[e];
    if (cn <= 0) return;

    __shared__ __align__(16) char Al[2][MT * 128];   // 2 x 32KB bf16 [m][chunk ^ (m&7)]
    __shared__ __align__(16) char Bl[2][BK * 512];   // 2 x 32KB fp32 [k][n] linear

    int t = threadIdx.x;
    int wid = t >> 6, lane = t & 63;
    int NS = kch / BK;
    int k0 = kc * kch;
    bool producer = (wid < 4);

    // ---- producer constants ----
    // B: wave w covers k-rows w*16+(l>>2); lane chunk base l&3, 8 chunks stride 4
    const char* ewE = (const char*)ew + (size_t)e * DIN * DOUT * 4 + (size_t)nt * NT * 4;
    const char* bsrc0 = ewE + (size_t)(k0 + wid * 16 + (lane >> 2)) * (DOUT * 4)
                      + (size_t)(lane & 3) * 16;
    int bdst_row = (wid * 16 + (lane >> 2)) * 512 + (lane & 3) * 16;
    // A: instr j covers rows (wid*8+j)*8 + (l>>3); source chunk (l&7)^((l>>3)&7)
    int asrc_off = (((lane & 7) ^ ((lane >> 3) & 7)) << 4);

    // ---- consumer constants ----
    int cw_ = wid - 4;
    int wm = cw_ >> 1, wn = cw_ & 1;
    int g = lane >> 4;
    int af_off[4][2];
    #pragma unroll
    for (int mi = 0; mi < 4; ++mi)
        #pragma unroll
        for (int kk = 0; kk < 2; ++kk) {
            int m = wm * 64 + mi * 16 + (lane & 15);
            af_off[mi][kk] = m * 128 + (((g + kk * 4) ^ (m & 7)) << 4);
        }
    int bn_off[4];
    #pragma unroll
    for (int ni = 0; ni < 4; ++ni)
        bn_off[ni] = (wn * 64 + ni * 16 + (lane & 15)) * 4;

    for (int row0 = 0; row0 < cn; row0 += MT) {
        int mloc = min(MT, cn - row0);

        // producer: per-lane A gather bases for its 8 DMA instrs
        const char* abase[8];
        if (producer) {
            #pragma unroll
            for (int jj = 0; jj < 8; ++jj) {
                int r = (wid * 8 + jj) * 8 + (lane >> 3);
                int rc = min(row0 + r, cn - 1);
                int row = rowlist[e * NB + rc] >> 1;
                abase[jj] = (const char*)xb + (size_t)row * (DIN * 2)
                          + (size_t)k0 * 2 + asrc_off;
            }
        }
        bool wact = !producer && (wm * 64 < mloc);

        f32x4 acc[4][4];
        #pragma unroll
        for (int i = 0; i < 4; ++i)
            #pragma unroll
            for (int jj = 0; jj < 4; ++jj) acc[i][jj] = (f32x4){0.f, 0.f, 0.f, 0.f};

#define STAGE(s_, buf_) {                                                     \
        const char* bs_ = bsrc0 + (size_t)(s_) * ((size_t)BK * DOUT * 4);     \
        f32x4 bv[8];                                                          \
        _Pragma("unroll")                                                     \
        for (int i = 0; i < 8; ++i)                                           \
            bv[i] = *(const f32x4*)(bs_ + i * 64);                            \
        _Pragma("unroll")                                                     \
        for (int i = 0; i < 8; ++i)                                           \
            *(f32x4*)(Bl[buf_] + bdst_row + i * 64) = bv[i];                  \
        size_t ao_ = (size_t)(s_) * (BK * 2);                                 \
        _Pragma("unroll")                                                     \
        for (int jj = 0; jj < 8; ++jj)                                        \
            gload_lds16(abase[jj] + ao_, (char*)Al[buf_] + (wid * 8 + jj) * 1024); }

        // prologue: producers fill buf 0
        if (producer) STAGE(0, 0);
        __syncthreads();

        for (int s = 0; s < NS; ++s) {
            int buf = s & 1;
            if (producer) {
                if (s + 1 < NS) STAGE(s + 1, buf ^ 1);
            } else if (wact) {
                const char* Ab = Al[buf];
                const char* Bb = Bl[buf];
                __builtin_amdgcn_s_setprio(1);
                #pragma unroll
                for (int kk = 0; kk < 2; ++kk) {
                    s16x8 af[4];
                    #pragma unroll
                    for (int mi = 0; mi < 4; ++mi)
                        af[mi] = *(const s16x8*)(Ab + af_off[mi][kk]);
                    #pragma unroll
                    for (int ni = 0; ni < 4; ++ni) {
                        const char* bp = Bb + (kk * 32 + g * 8) * 512 + bn_off[ni];
                        float v[8];
                        #pragma unroll
                        for (int j = 0; j < 8; ++j)
                            v[j] = *(const float*)(bp + j * 512);
                        union { u32x4 u; s16x8 v8; } bf;
                        bf.u[0] = cvt_pk(v[0], v[1]); bf.u[1] = cvt_pk(v[2], v[3]);
                        bf.u[2] = cvt_pk(v[4], v[5]); bf.u[3] = cvt_pk(v[6], v[7]);
                        #pragma unroll
                        for (int mi = 0; mi < 4; ++mi)
                            acc[mi][ni] = __builtin_amdgcn_mfma_f32_16x16x32_bf16(
                                af[mi], bf.v8, acc[mi][ni], 0, 0, 0);
                    }
                }
                __builtin_amdgcn_s_setprio(0);
            }
            __syncthreads();   // drains producer ds_writes + A-DMAs (all one step old)
        }
#undef STAGE

        // ---- epilogue (consumers): gate weight, bf16 scatter to partial planes ----
        if (wact) {
            #pragma unroll
            for (int mi = 0; mi < 4; ++mi) {
                #pragma unroll
                for (int rg = 0; rg < 4; ++rg) {
                    int m = wm * 64 + mi * 16 + g * 4 + rg;
                    if (m < mloc) {
                        int ent = rowlist[e * NB + row0 + m];
                        float wgt = roww[e * NB + row0 + m];
                        int ob = ent >> 1, slot = ent & 1;
                        unsigned short* dst = ypart + ((size_t)(slot * nkc + kc) * NB + ob) * DOUT
                                            + nt * NT + wn * 64 + (lane & 15);
                        #pragma unroll
                        for (int ni = 0; ni < 4; ++ni)
                            dst[ni * 16] = f2bf_u(acc[mi][ni][rg] * wgt);
                    }
                }
            }
        }
        __syncthreads();   // LDS safe before next (rare) row-tile
    }
}

// ---------------- Kernel D: combine bf16 partial planes + weighted expert bias ------------
__global__ __launch_bounds__(256) void kcombine(
    const unsigned short* __restrict__ ypart,
    const int* __restrict__ top2e, const float* __restrict__ top2w,
    const float* __restrict__ eb, float* __restrict__ out, int nplanes)
{
    int b = blockIdx.y;
    int n = blockIdx.x * 256 + threadIdx.x;
    float s = 0.f;
    for (int p = 0; p < nplanes; ++p) {
        unsigned v = ypart[((size_t)p * NB + b) * DOUT + n];
        union { unsigned u; float f; } c; c.u = v << 16;
        s += c.f;
    }
    int e0 = top2e[b * 2], e1 = top2e[b * 2 + 1];
    float w0 = top2w[b * 2], w1 = top2w[b * 2 + 1];
    s += w0 * eb[e0 * DOUT + n] + w1 * eb[e1 * DOUT + n];
    out[(size_t)b * DOUT + n] = s;
}

extern "C" void kernel_launch(void* const* d_in, const int* in_sizes, int n_in,
                              void* d_out, int out_size, void* d_ws, size_t ws_size,
                              hipStream_t stream)
{
    const float* x   = (const float*)d_in[0];
    const float* gu  = (const float*)d_in[1];
    const float* cw  = (const float*)d_in[2];
    const float* cb  = (const float*)d_in[3];
    const float* bng = (const float*)d_in[4];
    const float* bnb = (const float*)d_in[5];
    const float* bnm = (const float*)d_in[6];
    const float* bnv = (const float*)d_in[7];
    const float* f1w = (const float*)d_in[8];
    const float* f1b = (const float*)d_in[9];
    const float* f2w = (const float*)d_in[10];
    const float* f2b = (const float*)d_in[11];
    const float* ew  = (const float*)d_in[12];
    const float* eb  = (const float*)d_in[13];

    int nkc = (ws_size >= (size_t)48 * 1024 * 1024) ? 16 : 8;
    int kch = DIN / nkc;

    char* ws = (char*)d_ws;
    size_t off = 0;
    float* h       = (float*)(ws + off); off += (size_t)NB * HD * 4;
    int*   top2e   = (int*)(ws + off);   off += (size_t)NB * 2 * 4;
    float* top2w   = (float*)(ws + off); off += (size_t)NB * 2 * 4;
    int*   cnt     = (int*)(ws + off);   off += 256;
    int*   rowlist = (int*)(ws + off);   off += (size_t)NE * NB * 4;
    float* roww    = (float*)(ws + off); off += (size_t)NE * NB * 4;
    unsigned short* xbuf = (unsigned short*)(ws + off);
    off += (size_t)NB * DIN * 2;
    unsigned short* ypart = (unsigned short*)(ws + off);
    off += (size_t)2 * nkc * NB * DOUT * 2;

    krouter_conv<<<dim3(2, NB), 256, 0, stream>>>(x, cw, cb, bng, bnb, bnm, bnv, h, cnt, xbuf);
    krouter_fc<<<NB / 4, 256, 0, stream>>>(h, f1w, f1b, f2w, f2b, gu,
                                           top2e, top2w, cnt, rowlist, roww);
    kgemm<<<NE * nkc * 6, 768, 0, stream>>>(xbuf, ew, cnt, rowlist, roww, ypart, nkc, kch);
    kcombine<<<dim3(3, NB), 256, 0, stream>>>(ypart, top2e, top2w, eb, (float*)d_out, 2 * nkc);
}